// Round 12
// baseline (375.069 us; speedup 1.0000x reference)
//
#include <hip/hip_runtime.h>
#include <hip/hip_bf16.h>
#include <math.h>

// ---------------------------------------------------------------------------
// GAT: 2x GATConv(heads=1) + global mean pool + FC(64->2)
// R11: OBSERVABILITY round. Aggregate is pinned ~56us x2 (3 probes agree:
//      traffic-bound, per-XCD L2 duplication structural). 222us of runtime
//      hides below the 58us top-5 cutoff. So: (1) split each aggregate into
//      two node-range dispatches (~29us each) to lower the profile cutoff
//      and expose the hidden kernels; (2) fuse pool+fc into one graph-per-
//      block kernel (binary search on sorted batch, zero atomics);
//      (3) aggregate body back to proven R6 unroll x4 (VGPR 32, occ 63%);
//      (4) partition EPB 4096->2048 (782 blocks, 2x occupancy).
// ---------------------------------------------------------------------------

#define NPB 256          // nodes per bucket
#define EPB 2048         // edges per partition block (256 thr x 8)
#define PSTRIDE 4608     // slots per bucket (lambda=4092, +8 sigma)

__device__ __forceinline__ unsigned int f2bf(float v) {
    unsigned int b = __float_as_uint(v);
    b += 0x7FFFu + ((b >> 16) & 1u);   // round-to-nearest-even
    return b >> 16;
}

// --- init: zero bucket cursors ----------------------------------------------
__global__ __launch_bounds__(256) void init_all(int* __restrict__ bcur, int NB) {
    int i = blockIdx.x * 256 + threadIdx.x;
    if (i < NB) bcur[i] = 0;
}

// --- partition edges into fixed-stride dst-buckets (single pass) ------------
__global__ __launch_bounds__(256) void partition(const int* __restrict__ ei,
                                                 int E, int NB,
                                                 int* __restrict__ bcur,
                                                 uint2* __restrict__ pairs) {
    __shared__ int h[512];
    __shared__ int hb[512];
    int t = threadIdx.x;
    for (int i = t; i < 512; i += 256) h[i] = 0;
    __syncthreads();
    int i0 = blockIdx.x * EPB;
    int s[8], bk[8], r[8];
#pragma unroll
    for (int k = 0; k < 8; k++) {
        int i = i0 + k * 256 + t;
        bk[k] = -1;
        if (i < E) {
            s[k] = ei[i];
            int d = ei[E + i];
            bk[k] = d >> 8;
            r[k] = atomicAdd(&h[bk[k]], 1);
        }
    }
    __syncthreads();
    for (int b = t; b < NB; b += 256)
        hb[b] = h[b] ? atomicAdd(&bcur[b], h[b]) : 0;
    __syncthreads();
#pragma unroll
    for (int k = 0; k < 8; k++) {
        if (bk[k] < 0) continue;
        int i = i0 + k * 256 + t;
        int d = ei[E + i];                 // warm reload
        int pos = hb[bk[k]] + r[k];
        if (pos < PSTRIDE)                 // overflow guard (stat. impossible)
            pairs[(size_t)bk[k] * PSTRIDE + pos] =
                make_uint2((unsigned)s[k], (unsigned)d);
    }
}

// --- per-bucket CSR fill; bucket-count scan inlined (each block rescans) ----
__global__ __launch_bounds__(256) void build_csr(const uint2* __restrict__ pairs,
                                                 const int* __restrict__ bcur,
                                                 int n, int NB,
                                                 int* __restrict__ rowptr,
                                                 int* __restrict__ srcs) {
    int b = blockIdx.x, t = threadIdx.x;
    __shared__ int c[512];
    __shared__ int s2[256];
    __shared__ int sbase, stot;
    int c0 = (2 * t < NB) ? min(bcur[2 * t], PSTRIDE) : 0;
    int c1 = (2 * t + 1 < NB) ? min(bcur[2 * t + 1], PSTRIDE) : 0;
    c[2 * t] = c0; c[2 * t + 1] = c1;
    s2[t] = c0 + c1;
    __syncthreads();
    for (int o = 1; o < 256; o <<= 1) {
        int u = (t >= o) ? s2[t - o] : 0;
        __syncthreads();
        s2[t] += u;
        __syncthreads();
    }
    if (t == 0) {
        int p = b >> 1;
        int ex = s2[p] - (c[2 * p] + c[2 * p + 1]);
        sbase = ex + ((b & 1) ? c[b & ~1] : 0);
        stot = s2[255];
    }
    __syncthreads();
    int d0 = b << 8;
    int nb = min(NPB, n - d0);
    int cnt_b = c[b];
    int csr0 = sbase + d0;   // pairs before + one self-loop per node before
    const uint2* pb = pairs + (size_t)b * PSTRIDE;

    __shared__ int deg[NPB];
    __shared__ int cur[NPB];
    __shared__ int tmp[NPB];
    deg[t] = (t < nb) ? 1 : 0;   // self-loop
    __syncthreads();
    for (int j = t; j < cnt_b; j += 256)
        atomicAdd(&deg[pb[j].y - d0], 1);
    __syncthreads();
    int v = deg[t];
    tmp[t] = v;
    __syncthreads();
    for (int o = 1; o < NPB; o <<= 1) {
        int u = (t >= o) ? tmp[t - o] : 0;
        __syncthreads();
        tmp[t] += u;
        __syncthreads();
    }
    int excl = tmp[t] - v;
    if (t < nb) {
        rowptr[d0 + t] = csr0 + excl;
        srcs[csr0 + excl] = d0 + t;   // self-loop at slot 0
        cur[t] = excl + 1;
    }
    __syncthreads();
    for (int j = t; j < cnt_b; j += 256) {
        uint2 p = pb[j];
        int off = atomicAdd(&cur[p.y - d0], 1);
        srcs[csr0 + off] = (int)p.x;
    }
    if (b == 0 && t == 0) rowptr[n] = n + stot;
}

// --- tiled node GEMM: 64 nodes x 64 cols per block, 4x4 per thread ----------
template <int IN_DIM>
__global__ __launch_bounds__(256) void node_gemm(const float* __restrict__ x,
                                                 const float* __restrict__ W,
                                                 const float* __restrict__ a_src,
                                                 const float* __restrict__ a_dst,
                                                 const float* __restrict__ bias_in,
                                                 float slope_in,
                                                 unsigned short* __restrict__ h16,
                                                 float* __restrict__ al_s,
                                                 float* __restrict__ al_d,
                                                 int n) {
    __shared__ float Ws[IN_DIM * 64];
    __shared__ float xs[IN_DIM][64];   // [k][node] — conflict-free both ways
    int t = threadIdx.x;
    int nbase = blockIdx.x * 64;

    for (int idx = t; idx < IN_DIM * 16; idx += 256)
        ((float4*)Ws)[idx] = ((const float4*)W)[idx];
    for (int idx = t; idx < IN_DIM * 64; idx += 256) {
        int node = nbase + (idx & 63);
        int k = idx >> 6;
        float v = 0.0f;
        if (node < n) {
            v = x[(size_t)node * IN_DIM + k];
            if (bias_in) {
                v += bias_in[k];
                v = (v >= 0.0f) ? v : slope_in * v;
            }
        }
        xs[k][idx & 63] = v;
    }
    __syncthreads();

    int cg = t & 15;    // col group: cols 4cg..4cg+3
    int ng = t >> 4;    // node group: nodes 4ng..4ng+3
    float acc[4][4] = {};
#pragma unroll 8
    for (int k = 0; k < IN_DIM; k++) {
        float4 xv = *(const float4*)&xs[k][ng * 4];
        float4 wv = *(const float4*)&Ws[k * 64 + cg * 4];
        float xa[4] = {xv.x, xv.y, xv.z, xv.w};
        float wa[4] = {wv.x, wv.y, wv.z, wv.w};
#pragma unroll
        for (int i = 0; i < 4; i++)
#pragma unroll
            for (int j = 0; j < 4; j++)
                acc[i][j] += xa[i] * wa[j];
    }

    float4 as4 = *(const float4*)(a_src + cg * 4);
    float4 ad4 = *(const float4*)(a_dst + cg * 4);
#pragma unroll
    for (int i = 0; i < 4; i++) {
        int node = nbase + ng * 4 + i;
        if (node < n) {
            uint2 p;
            p.x = f2bf(acc[i][0]) | (f2bf(acc[i][1]) << 16);
            p.y = f2bf(acc[i][2]) | (f2bf(acc[i][3]) << 16);
            *(uint2*)(h16 + (size_t)node * 64 + cg * 4) = p;
        }
        float vs = acc[i][0] * as4.x + acc[i][1] * as4.y +
                   acc[i][2] * as4.z + acc[i][3] * as4.w;
        float vd = acc[i][0] * ad4.x + acc[i][1] * ad4.y +
                   acc[i][2] * ad4.z + acc[i][3] * ad4.w;
#pragma unroll
        for (int o = 8; o; o >>= 1) {
            vs += __shfl_xor(vs, o);
            vd += __shfl_xor(vd, o);
        }
        if (cg == 0 && node < n) { al_s[node] = vs; al_d[node] = vd; }
    }
}

// --- single-pass aggregate (R6 proven body), node-range dispatch ------------
// out[node] = (sum_j exp(e_j)*h[src_j]) / (sum_j exp(e_j) + 1e-16)
__device__ __forceinline__ void bf8_fma(float* acc, uint4 q, float w) {
    acc[0] += w * __uint_as_float(q.x << 16);
    acc[1] += w * __uint_as_float(q.x & 0xFFFF0000u);
    acc[2] += w * __uint_as_float(q.y << 16);
    acc[3] += w * __uint_as_float(q.y & 0xFFFF0000u);
    acc[4] += w * __uint_as_float(q.z << 16);
    acc[5] += w * __uint_as_float(q.z & 0xFFFF0000u);
    acc[6] += w * __uint_as_float(q.w << 16);
    acc[7] += w * __uint_as_float(q.w & 0xFFFF0000u);
}

__global__ __launch_bounds__(256) void gat_aggregate(const int* __restrict__ rowptr,
                                                     const int* __restrict__ srcs,
                                                     const float* __restrict__ als,
                                                     const float* __restrict__ ald,
                                                     const unsigned short* __restrict__ h16,
                                                     float* __restrict__ hout,
                                                     int n0, int n1) {
    int t = threadIdx.x;
    int sub = t >> 3, lane = t & 7;       // 32 nodes/block, 8 lanes/node
    int node = n0 + blockIdx.x * 32 + sub;
    if (node >= n1) return;
    int beg = rowptr[node], end = rowptr[node + 1];
    float aldv = ald[node];
    const unsigned short* hb = h16 + lane * 8;

    float acc[8] = {};
    float sm = 0.0f;
    int j = beg;
    for (; j + 4 <= end; j += 4) {
        int s0 = srcs[j], s1 = srcs[j + 1], s2 = srcs[j + 2], s3 = srcs[j + 3];
        float e0 = als[s0] + aldv, e1 = als[s1] + aldv;
        float e2 = als[s2] + aldv, e3 = als[s3] + aldv;
        uint4 q0 = *(const uint4*)(hb + (size_t)s0 * 64);
        uint4 q1 = *(const uint4*)(hb + (size_t)s1 * 64);
        uint4 q2 = *(const uint4*)(hb + (size_t)s2 * 64);
        uint4 q3 = *(const uint4*)(hb + (size_t)s3 * 64);
        e0 = (e0 >= 0.0f) ? e0 : 0.2f * e0;
        e1 = (e1 >= 0.0f) ? e1 : 0.2f * e1;
        e2 = (e2 >= 0.0f) ? e2 : 0.2f * e2;
        e3 = (e3 >= 0.0f) ? e3 : 0.2f * e3;
        float w0 = __expf(e0), w1 = __expf(e1);
        float w2 = __expf(e2), w3 = __expf(e3);
        sm += (w0 + w1) + (w2 + w3);
        bf8_fma(acc, q0, w0);
        bf8_fma(acc, q1, w1);
        bf8_fma(acc, q2, w2);
        bf8_fma(acc, q3, w3);
    }
    for (; j < end; j++) {
        int s = srcs[j];
        float e = als[s] + aldv;
        e = (e >= 0.0f) ? e : 0.2f * e;
        float w = __expf(e);
        uint4 q = *(const uint4*)(hb + (size_t)s * 64);
        sm += w;
        bf8_fma(acc, q, w);
    }

    float inv = 1.0f / (sm + 1e-16f);
    float4 o0 = make_float4(acc[0] * inv, acc[1] * inv, acc[2] * inv, acc[3] * inv);
    float4 o1 = make_float4(acc[4] * inv, acc[5] * inv, acc[6] * inv, acc[7] * inv);
    float* op = hout + (size_t)node * 64 + lane * 8;
    *(float4*)op = o0;
    *(float4*)(op + 4) = o1;
}

// --- fused pool + FC: one block per graph, binary-search batch bounds -------
// out[g] = ((sum_{batch=g} hout + cnt*b2) / max(cnt,1)) @ fcW + fcb
__global__ __launch_bounds__(256) void pool_fc(const float* __restrict__ hout,
                                               const float* __restrict__ b2,
                                               const int* __restrict__ batch,
                                               const float* __restrict__ fcW,
                                               const float* __restrict__ fcb,
                                               float* __restrict__ out, int n) {
    int g = blockIdx.x;
    int t = threadIdx.x;
    __shared__ int sLo, sHi;
    __shared__ float red[4][64];
    if (t == 0) {
        int lo = 0, hi = n;
        while (lo < hi) { int m = (lo + hi) >> 1; if (batch[m] < g) lo = m + 1; else hi = m; }
        sLo = lo;
    } else if (t == 64) {
        int lo = 0, hi = n;
        while (lo < hi) { int m = (lo + hi) >> 1; if (batch[m] < g + 1) lo = m + 1; else hi = m; }
        sHi = lo;
    }
    __syncthreads();
    int lo = sLo, hi = sHi;
    int wv = t >> 6, lane = t & 63;
    float acc = 0.0f;
    for (int node = lo + wv; node < hi; node += 4)
        acc += hout[(size_t)node * 64 + lane];
    red[wv][lane] = acc;
    __syncthreads();
    if (wv == 0) {
        float c = (float)(hi - lo);
        float s = red[0][lane] + red[1][lane] + red[2][lane] + red[3][lane];
        s += c * b2[lane];
        float cd = (c > 1.0f) ? c : 1.0f;
        float p = s / cd;
        float s0 = p * fcW[lane * 2 + 0];
        float s1 = p * fcW[lane * 2 + 1];
#pragma unroll
        for (int o = 32; o; o >>= 1) {
            s0 += __shfl_xor(s0, o);
            s1 += __shfl_xor(s1, o);
        }
        if (lane == 0) {
            out[g * 2 + 0] = s0 + fcb[0];
            out[g * 2 + 1] = s1 + fcb[1];
        }
    }
}

extern "C" void kernel_launch(void* const* d_in, const int* in_sizes, int n_in,
                              void* d_out, int out_size, void* d_ws, size_t ws_size,
                              hipStream_t stream) {
    const float* x    = (const float*)d_in[0];
    const int*   ei   = (const int*)d_in[1];
    const int*   batch= (const int*)d_in[2];
    const float* W1   = (const float*)d_in[3];
    const float* as1  = (const float*)d_in[4];
    const float* ad1  = (const float*)d_in[5];
    const float* b1   = (const float*)d_in[6];
    const float* W2   = (const float*)d_in[7];
    const float* as2  = (const float*)d_in[8];
    const float* ad2  = (const float*)d_in[9];
    const float* b2   = (const float*)d_in[10];
    const float* fcW  = (const float*)d_in[11];
    const float* fcb  = (const float*)d_in[12];
    float* out = (float*)d_out;

    const int N = in_sizes[2];       // 100000
    const int E = in_sizes[1] / 2;   // 1600000
    const int G = out_size / 2;      // 256
    const int tot = E + N;
    const int NB = (N + NPB - 1) / NPB;   // 391 buckets

    // ws layout (~61 MiB): pairs is stride-padded (NB*PSTRIDE slots)
    float* ws     = (float*)d_ws;
    float* bufO   = ws;                           // N*64 fp32        25.6 MB
    uint2* pairs  = (uint2*)(bufO + (size_t)N * 64);   // NB*PSTRIDE  14.4 MB
    float* als    = (float*)(pairs + (size_t)NB * PSTRIDE);  // N      0.4 MB
    float* ald    = als + N;                      // N                 0.4 MB
    int*   rowptr = (int*)(ald + N);              // N+1               0.4 MB
    int*   srcs   = rowptr + N + 1;               // tot               6.8 MB
    int*   bcur   = srcs + tot;                   // NB
    unsigned short* bufH16 = (unsigned short*)(bcur + NB);  // N*64   12.8 MB

    dim3 b256(256);
    int gInit = (NB + 255) / 256;
    int gPart = (E + EPB - 1) / EPB;
    int gGemm = (N + 63) / 64;
    // node-range split for the aggregate (halves, 32-aligned)
    int H = (((N + 1) / 2 + 31) / 32) * 32;
    int gAgg1 = (H + 31) / 32;
    int gAgg2 = (N - H + 31) / 32;

    // ---- CSR build: single-pass fixed-stride partition + fill (edges only) --
    init_all<<<gInit, b256, 0, stream>>>(bcur, NB);
    partition<<<gPart, b256, 0, stream>>>(ei, E, NB, bcur, pairs);
    build_csr<<<NB, b256, 0, stream>>>(pairs, bcur, N, NB, rowptr, srcs);

    // ---- layer 1 ----
    node_gemm<72><<<gGemm, b256, 0, stream>>>(x, W1, as1, ad1, nullptr, 0.0f,
                                              bufH16, als, ald, N);
    gat_aggregate<<<gAgg1, b256, 0, stream>>>(rowptr, srcs, als, ald, bufH16, bufO, 0, H);
    gat_aggregate<<<gAgg2, b256, 0, stream>>>(rowptr, srcs, als, ald, bufH16, bufO, H, N);

    // ---- layer 2 (input = leaky(bufO + b1, 0.01)) ----
    node_gemm<64><<<gGemm, b256, 0, stream>>>(bufO, W2, as2, ad2, b1, 0.01f,
                                              bufH16, als, ald, N);
    gat_aggregate<<<gAgg1, b256, 0, stream>>>(rowptr, srcs, als, ald, bufH16, bufO, 0, H);
    gat_aggregate<<<gAgg2, b256, 0, stream>>>(rowptr, srcs, als, ald, bufH16, bufO, H, N);

    // ---- fused pool + fc ----
    pool_fc<<<G, b256, 0, stream>>>(bufO, b2, batch, fcW, fcb, out, N);
}

// Round 13
// 336.946 us; speedup vs baseline: 1.1131x; 1.1131x over previous
//
#include <hip/hip_runtime.h>
#include <hip/hip_bf16.h>
#include <math.h>

// ---------------------------------------------------------------------------
// GAT: 2x GATConv(heads=1) + global mean pool + FC(64->2)
// R13: consolidation. (1) EPB back to 4096 (2048 regressed: 2x per-block
//      fixed cost + 40B partial-line pair writes -> 42MB WRITE). (2) pairs
//      packed to uint32 (src|dlow<<24): halves partition write + csr read,
//      no 3rd ei pass. (3) GEMM x-staging linearized -> fully coalesced
//      global reads (was 64-transaction stride-288B scatter). (4) aggregate
//      back to one dispatch/layer (R6 proven body); pool_fc fusion kept.
// ---------------------------------------------------------------------------

#define NPB 256          // nodes per bucket
#define EPB 4096         // edges per partition block (256 thr x 16)
#define PSTRIDE 4608     // slots per bucket (lambda=4092, +8 sigma)

__device__ __forceinline__ unsigned int f2bf(float v) {
    unsigned int b = __float_as_uint(v);
    b += 0x7FFFu + ((b >> 16) & 1u);   // round-to-nearest-even
    return b >> 16;
}

// --- init: zero bucket cursors ----------------------------------------------
__global__ __launch_bounds__(256) void init_all(int* __restrict__ bcur, int NB) {
    int i = blockIdx.x * 256 + threadIdx.x;
    if (i < NB) bcur[i] = 0;
}

// --- partition edges into fixed-stride dst-buckets (packed uint32) ----------
__global__ __launch_bounds__(256) void partition(const int* __restrict__ ei,
                                                 int E, int NB,
                                                 int* __restrict__ bcur,
                                                 unsigned int* __restrict__ pairs) {
    __shared__ int h[512];
    __shared__ int hb[512];
    int t = threadIdx.x;
    for (int i = t; i < 512; i += 256) h[i] = 0;
    __syncthreads();
    int i0 = blockIdx.x * EPB;
    unsigned int val[16];
    int bk[16], r[16];
#pragma unroll
    for (int k = 0; k < 16; k++) {
        int i = i0 + k * 256 + t;
        bk[k] = -1;
        if (i < E) {
            int s = ei[i];
            int d = ei[E + i];
            bk[k] = d >> 8;
            val[k] = (unsigned)s | ((unsigned)(d & 255) << 24);
            r[k] = atomicAdd(&h[bk[k]], 1);
        }
    }
    __syncthreads();
    for (int b = t; b < NB; b += 256)
        hb[b] = h[b] ? atomicAdd(&bcur[b], h[b]) : 0;
    __syncthreads();
#pragma unroll
    for (int k = 0; k < 16; k++) {
        if (bk[k] < 0) continue;
        int pos = hb[bk[k]] + r[k];
        if (pos < PSTRIDE)                 // overflow guard (stat. impossible)
            pairs[(size_t)bk[k] * PSTRIDE + pos] = val[k];
    }
}

// --- per-bucket CSR fill; bucket-count scan inlined (each block rescans) ----
__global__ __launch_bounds__(256) void build_csr(const unsigned int* __restrict__ pairs,
                                                 const int* __restrict__ bcur,
                                                 int n, int NB,
                                                 int* __restrict__ rowptr,
                                                 int* __restrict__ srcs) {
    int b = blockIdx.x, t = threadIdx.x;
    __shared__ int c[512];
    __shared__ int s2[256];
    __shared__ int sbase, stot;
    int c0 = (2 * t < NB) ? min(bcur[2 * t], PSTRIDE) : 0;
    int c1 = (2 * t + 1 < NB) ? min(bcur[2 * t + 1], PSTRIDE) : 0;
    c[2 * t] = c0; c[2 * t + 1] = c1;
    s2[t] = c0 + c1;
    __syncthreads();
    for (int o = 1; o < 256; o <<= 1) {
        int u = (t >= o) ? s2[t - o] : 0;
        __syncthreads();
        s2[t] += u;
        __syncthreads();
    }
    if (t == 0) {
        int p = b >> 1;
        int ex = s2[p] - (c[2 * p] + c[2 * p + 1]);
        sbase = ex + ((b & 1) ? c[b & ~1] : 0);
        stot = s2[255];
    }
    __syncthreads();
    int d0 = b << 8;
    int nb = min(NPB, n - d0);
    int cnt_b = c[b];
    int csr0 = sbase + d0;   // pairs before + one self-loop per node before
    const unsigned int* pb = pairs + (size_t)b * PSTRIDE;

    __shared__ int deg[NPB];
    __shared__ int cur[NPB];
    __shared__ int tmp[NPB];
    deg[t] = (t < nb) ? 1 : 0;   // self-loop
    __syncthreads();
    for (int j = t; j < cnt_b; j += 256)
        atomicAdd(&deg[pb[j] >> 24], 1);
    __syncthreads();
    int v = deg[t];
    tmp[t] = v;
    __syncthreads();
    for (int o = 1; o < NPB; o <<= 1) {
        int u = (t >= o) ? tmp[t - o] : 0;
        __syncthreads();
        tmp[t] += u;
        __syncthreads();
    }
    int excl = tmp[t] - v;
    if (t < nb) {
        rowptr[d0 + t] = csr0 + excl;
        srcs[csr0 + excl] = d0 + t;   // self-loop at slot 0
        cur[t] = excl + 1;
    }
    __syncthreads();
    for (int j = t; j < cnt_b; j += 256) {
        unsigned int p = pb[j];
        int off = atomicAdd(&cur[p >> 24], 1);
        srcs[csr0 + off] = (int)(p & 0x00FFFFFFu);
    }
    if (b == 0 && t == 0) rowptr[n] = n + stot;
}

// --- tiled node GEMM: 64 nodes x 64 cols per block, 4x4 per thread ----------
// x-staging is a LINEAR copy of the 64-row block (coalesced), scattered into
// xs[k][node] in LDS (write conflicts ~1us total, vs 16x VMEM transactions).
template <int IN_DIM>
__global__ __launch_bounds__(256) void node_gemm(const float* __restrict__ x,
                                                 const float* __restrict__ W,
                                                 const float* __restrict__ a_src,
                                                 const float* __restrict__ a_dst,
                                                 const float* __restrict__ bias_in,
                                                 float slope_in,
                                                 unsigned short* __restrict__ h16,
                                                 float* __restrict__ al_s,
                                                 float* __restrict__ al_d,
                                                 int n) {
    __shared__ float Ws[IN_DIM * 64];
    __shared__ float xs[IN_DIM][64];
    int t = threadIdx.x;
    int nbase = blockIdx.x * 64;

    for (int idx = t; idx < IN_DIM * 16; idx += 256)
        ((float4*)Ws)[idx] = ((const float4*)W)[idx];
    const float* xb = x + (size_t)nbase * IN_DIM;
    int lim = min(64, n - nbase) * IN_DIM;
    for (int idx = t; idx < 64 * IN_DIM; idx += 256) {
        int node = idx / IN_DIM;
        int k = idx - node * IN_DIM;
        float v = 0.0f;
        if (idx < lim) {
            v = xb[idx];                       // contiguous, fully coalesced
            if (bias_in) {
                v += bias_in[k];
                v = (v >= 0.0f) ? v : slope_in * v;
            }
        }
        xs[k][node] = v;
    }
    __syncthreads();

    int cg = t & 15;    // col group: cols 4cg..4cg+3
    int ng = t >> 4;    // node group: nodes 4ng..4ng+3
    float acc[4][4] = {};
#pragma unroll 8
    for (int k = 0; k < IN_DIM; k++) {
        float4 xv = *(const float4*)&xs[k][ng * 4];
        float4 wv = *(const float4*)&Ws[k * 64 + cg * 4];
        float xa[4] = {xv.x, xv.y, xv.z, xv.w};
        float wa[4] = {wv.x, wv.y, wv.z, wv.w};
#pragma unroll
        for (int i = 0; i < 4; i++)
#pragma unroll
            for (int j = 0; j < 4; j++)
                acc[i][j] += xa[i] * wa[j];
    }

    float4 as4 = *(const float4*)(a_src + cg * 4);
    float4 ad4 = *(const float4*)(a_dst + cg * 4);
#pragma unroll
    for (int i = 0; i < 4; i++) {
        int node = nbase + ng * 4 + i;
        if (node < n) {
            uint2 p;
            p.x = f2bf(acc[i][0]) | (f2bf(acc[i][1]) << 16);
            p.y = f2bf(acc[i][2]) | (f2bf(acc[i][3]) << 16);
            *(uint2*)(h16 + (size_t)node * 64 + cg * 4) = p;
        }
        float vs = acc[i][0] * as4.x + acc[i][1] * as4.y +
                   acc[i][2] * as4.z + acc[i][3] * as4.w;
        float vd = acc[i][0] * ad4.x + acc[i][1] * ad4.y +
                   acc[i][2] * ad4.z + acc[i][3] * ad4.w;
#pragma unroll
        for (int o = 8; o; o >>= 1) {
            vs += __shfl_xor(vs, o);
            vd += __shfl_xor(vd, o);
        }
        if (cg == 0 && node < n) { al_s[node] = vs; al_d[node] = vd; }
    }
}

// --- single-pass aggregate (R6 proven body): 8 lanes/node, unroll x4 --------
// out[node] = (sum_j exp(e_j)*h[src_j]) / (sum_j exp(e_j) + 1e-16)
__device__ __forceinline__ void bf8_fma(float* acc, uint4 q, float w) {
    acc[0] += w * __uint_as_float(q.x << 16);
    acc[1] += w * __uint_as_float(q.x & 0xFFFF0000u);
    acc[2] += w * __uint_as_float(q.y << 16);
    acc[3] += w * __uint_as_float(q.y & 0xFFFF0000u);
    acc[4] += w * __uint_as_float(q.z << 16);
    acc[5] += w * __uint_as_float(q.z & 0xFFFF0000u);
    acc[6] += w * __uint_as_float(q.w << 16);
    acc[7] += w * __uint_as_float(q.w & 0xFFFF0000u);
}

__global__ __launch_bounds__(256) void gat_aggregate(const int* __restrict__ rowptr,
                                                     const int* __restrict__ srcs,
                                                     const float* __restrict__ als,
                                                     const float* __restrict__ ald,
                                                     const unsigned short* __restrict__ h16,
                                                     float* __restrict__ hout,
                                                     int n) {
    int t = threadIdx.x;
    int sub = t >> 3, lane = t & 7;       // 32 nodes/block, 8 lanes/node
    int node = blockIdx.x * 32 + sub;
    if (node >= n) return;
    int beg = rowptr[node], end = rowptr[node + 1];
    float aldv = ald[node];
    const unsigned short* hb = h16 + lane * 8;

    float acc[8] = {};
    float sm = 0.0f;
    int j = beg;
    for (; j + 4 <= end; j += 4) {
        int s0 = srcs[j], s1 = srcs[j + 1], s2 = srcs[j + 2], s3 = srcs[j + 3];
        float e0 = als[s0] + aldv, e1 = als[s1] + aldv;
        float e2 = als[s2] + aldv, e3 = als[s3] + aldv;
        uint4 q0 = *(const uint4*)(hb + (size_t)s0 * 64);
        uint4 q1 = *(const uint4*)(hb + (size_t)s1 * 64);
        uint4 q2 = *(const uint4*)(hb + (size_t)s2 * 64);
        uint4 q3 = *(const uint4*)(hb + (size_t)s3 * 64);
        e0 = (e0 >= 0.0f) ? e0 : 0.2f * e0;
        e1 = (e1 >= 0.0f) ? e1 : 0.2f * e1;
        e2 = (e2 >= 0.0f) ? e2 : 0.2f * e2;
        e3 = (e3 >= 0.0f) ? e3 : 0.2f * e3;
        float w0 = __expf(e0), w1 = __expf(e1);
        float w2 = __expf(e2), w3 = __expf(e3);
        sm += (w0 + w1) + (w2 + w3);
        bf8_fma(acc, q0, w0);
        bf8_fma(acc, q1, w1);
        bf8_fma(acc, q2, w2);
        bf8_fma(acc, q3, w3);
    }
    for (; j < end; j++) {
        int s = srcs[j];
        float e = als[s] + aldv;
        e = (e >= 0.0f) ? e : 0.2f * e;
        float w = __expf(e);
        uint4 q = *(const uint4*)(hb + (size_t)s * 64);
        sm += w;
        bf8_fma(acc, q, w);
    }

    float inv = 1.0f / (sm + 1e-16f);
    float4 o0 = make_float4(acc[0] * inv, acc[1] * inv, acc[2] * inv, acc[3] * inv);
    float4 o1 = make_float4(acc[4] * inv, acc[5] * inv, acc[6] * inv, acc[7] * inv);
    float* op = hout + (size_t)node * 64 + lane * 8;
    *(float4*)op = o0;
    *(float4*)(op + 4) = o1;
}

// --- fused pool + FC: one block per graph, binary-search batch bounds -------
__global__ __launch_bounds__(256) void pool_fc(const float* __restrict__ hout,
                                               const float* __restrict__ b2,
                                               const int* __restrict__ batch,
                                               const float* __restrict__ fcW,
                                               const float* __restrict__ fcb,
                                               float* __restrict__ out, int n) {
    int g = blockIdx.x;
    int t = threadIdx.x;
    __shared__ int sLo, sHi;
    __shared__ float red[4][64];
    if (t == 0) {
        int lo = 0, hi = n;
        while (lo < hi) { int m = (lo + hi) >> 1; if (batch[m] < g) lo = m + 1; else hi = m; }
        sLo = lo;
    } else if (t == 64) {
        int lo = 0, hi = n;
        while (lo < hi) { int m = (lo + hi) >> 1; if (batch[m] < g + 1) lo = m + 1; else hi = m; }
        sHi = lo;
    }
    __syncthreads();
    int lo = sLo, hi = sHi;
    int wv = t >> 6, lane = t & 63;
    float acc = 0.0f;
    for (int node = lo + wv; node < hi; node += 4)
        acc += hout[(size_t)node * 64 + lane];
    red[wv][lane] = acc;
    __syncthreads();
    if (wv == 0) {
        float c = (float)(hi - lo);
        float s = red[0][lane] + red[1][lane] + red[2][lane] + red[3][lane];
        s += c * b2[lane];
        float cd = (c > 1.0f) ? c : 1.0f;
        float p = s / cd;
        float s0 = p * fcW[lane * 2 + 0];
        float s1 = p * fcW[lane * 2 + 1];
#pragma unroll
        for (int o = 32; o; o >>= 1) {
            s0 += __shfl_xor(s0, o);
            s1 += __shfl_xor(s1, o);
        }
        if (lane == 0) {
            out[g * 2 + 0] = s0 + fcb[0];
            out[g * 2 + 1] = s1 + fcb[1];
        }
    }
}

extern "C" void kernel_launch(void* const* d_in, const int* in_sizes, int n_in,
                              void* d_out, int out_size, void* d_ws, size_t ws_size,
                              hipStream_t stream) {
    const float* x    = (const float*)d_in[0];
    const int*   ei   = (const int*)d_in[1];
    const int*   batch= (const int*)d_in[2];
    const float* W1   = (const float*)d_in[3];
    const float* as1  = (const float*)d_in[4];
    const float* ad1  = (const float*)d_in[5];
    const float* b1   = (const float*)d_in[6];
    const float* W2   = (const float*)d_in[7];
    const float* as2  = (const float*)d_in[8];
    const float* ad2  = (const float*)d_in[9];
    const float* b2   = (const float*)d_in[10];
    const float* fcW  = (const float*)d_in[11];
    const float* fcb  = (const float*)d_in[12];
    float* out = (float*)d_out;

    const int N = in_sizes[2];       // 100000
    const int E = in_sizes[1] / 2;   // 1600000
    const int G = out_size / 2;      // 256
    const int tot = E + N;
    const int NB = (N + NPB - 1) / NPB;   // 391 buckets

    // ws layout (~54 MiB): pairs is packed uint32, stride-padded
    float* ws     = (float*)d_ws;
    float* bufO   = ws;                           // N*64 fp32        25.6 MB
    unsigned int* pairs = (unsigned int*)(bufO + (size_t)N * 64); // 7.2 MB
    float* als    = (float*)(pairs + (size_t)NB * PSTRIDE);  // N      0.4 MB
    float* ald    = als + N;                      // N                 0.4 MB
    int*   rowptr = (int*)(ald + N);              // N+1               0.4 MB
    int*   srcs   = rowptr + N + 1;               // tot               6.8 MB
    int*   bcur   = srcs + tot;                   // NB
    unsigned short* bufH16 = (unsigned short*)(bcur + NB);  // N*64   12.8 MB

    dim3 b256(256);
    int gInit = (NB + 255) / 256;
    int gPart = (E + EPB - 1) / EPB;
    int gGemm = (N + 63) / 64;
    int gAgg  = (N + 31) / 32;

    // ---- CSR build: single-pass fixed-stride partition + fill (edges only) --
    init_all<<<gInit, b256, 0, stream>>>(bcur, NB);
    partition<<<gPart, b256, 0, stream>>>(ei, E, NB, bcur, pairs);
    build_csr<<<NB, b256, 0, stream>>>(pairs, bcur, N, NB, rowptr, srcs);

    // ---- layer 1 ----
    node_gemm<72><<<gGemm, b256, 0, stream>>>(x, W1, as1, ad1, nullptr, 0.0f,
                                              bufH16, als, ald, N);
    gat_aggregate<<<gAgg, b256, 0, stream>>>(rowptr, srcs, als, ald, bufH16, bufO, N);

    // ---- layer 2 (input = leaky(bufO + b1, 0.01)) ----
    node_gemm<64><<<gGemm, b256, 0, stream>>>(bufO, W2, as2, ad2, b1, 0.01f,
                                              bufH16, als, ald, N);
    gat_aggregate<<<gAgg, b256, 0, stream>>>(rowptr, srcs, als, ald, bufH16, bufO, N);

    // ---- fused pool + fc ----
    pool_fc<<<G, b256, 0, stream>>>(bufO, b2, batch, fcW, fcb, out, N);
}

// Round 14
// 335.073 us; speedup vs baseline: 1.1194x; 1.0056x over previous
//
#include <hip/hip_runtime.h>
#include <hip/hip_bf16.h>
#include <math.h>

// ---------------------------------------------------------------------------
// GAT: 2x GATConv(heads=1) + global mean pool + FC(64->2)
// R14 = R13 + one fix: pad GEMM x-stage LDS to [IN_DIM][68].
//      R13's linear (coalesced) staging wrote xs[k][node] at stride 64 floats
//      -> all 64 lanes hit bank=node%32 = 64-way write conflict (~+10us/gemm,
//      exactly cancelling the coalescing gain; R13 == R11 total). Stride 68
//      -> bank=(4k+node)%32 -> 8-way (free-ish); reads stay 16B-aligned
//      (68*4=272 = 0 mod 16) so ds_read_b128 is preserved.
// Everything else byte-identical to R13 (best: 336.9us).
// ---------------------------------------------------------------------------

#define NPB 256          // nodes per bucket
#define EPB 4096         // edges per partition block (256 thr x 16)
#define PSTRIDE 4608     // slots per bucket (lambda=4092, +8 sigma)
#define XPAD 68          // xs leading-dim pad: 8-way banks, 16B-aligned rows

__device__ __forceinline__ unsigned int f2bf(float v) {
    unsigned int b = __float_as_uint(v);
    b += 0x7FFFu + ((b >> 16) & 1u);   // round-to-nearest-even
    return b >> 16;
}

// --- init: zero bucket cursors ----------------------------------------------
__global__ __launch_bounds__(256) void init_all(int* __restrict__ bcur, int NB) {
    int i = blockIdx.x * 256 + threadIdx.x;
    if (i < NB) bcur[i] = 0;
}

// --- partition edges into fixed-stride dst-buckets (packed uint32) ----------
__global__ __launch_bounds__(256) void partition(const int* __restrict__ ei,
                                                 int E, int NB,
                                                 int* __restrict__ bcur,
                                                 unsigned int* __restrict__ pairs) {
    __shared__ int h[512];
    __shared__ int hb[512];
    int t = threadIdx.x;
    for (int i = t; i < 512; i += 256) h[i] = 0;
    __syncthreads();
    int i0 = blockIdx.x * EPB;
    unsigned int val[16];
    int bk[16], r[16];
#pragma unroll
    for (int k = 0; k < 16; k++) {
        int i = i0 + k * 256 + t;
        bk[k] = -1;
        if (i < E) {
            int s = ei[i];
            int d = ei[E + i];
            bk[k] = d >> 8;
            val[k] = (unsigned)s | ((unsigned)(d & 255) << 24);
            r[k] = atomicAdd(&h[bk[k]], 1);
        }
    }
    __syncthreads();
    for (int b = t; b < NB; b += 256)
        hb[b] = h[b] ? atomicAdd(&bcur[b], h[b]) : 0;
    __syncthreads();
#pragma unroll
    for (int k = 0; k < 16; k++) {
        if (bk[k] < 0) continue;
        int pos = hb[bk[k]] + r[k];
        if (pos < PSTRIDE)                 // overflow guard (stat. impossible)
            pairs[(size_t)bk[k] * PSTRIDE + pos] = val[k];
    }
}

// --- per-bucket CSR fill; bucket-count scan inlined (each block rescans) ----
__global__ __launch_bounds__(256) void build_csr(const unsigned int* __restrict__ pairs,
                                                 const int* __restrict__ bcur,
                                                 int n, int NB,
                                                 int* __restrict__ rowptr,
                                                 int* __restrict__ srcs) {
    int b = blockIdx.x, t = threadIdx.x;
    __shared__ int c[512];
    __shared__ int s2[256];
    __shared__ int sbase, stot;
    int c0 = (2 * t < NB) ? min(bcur[2 * t], PSTRIDE) : 0;
    int c1 = (2 * t + 1 < NB) ? min(bcur[2 * t + 1], PSTRIDE) : 0;
    c[2 * t] = c0; c[2 * t + 1] = c1;
    s2[t] = c0 + c1;
    __syncthreads();
    for (int o = 1; o < 256; o <<= 1) {
        int u = (t >= o) ? s2[t - o] : 0;
        __syncthreads();
        s2[t] += u;
        __syncthreads();
    }
    if (t == 0) {
        int p = b >> 1;
        int ex = s2[p] - (c[2 * p] + c[2 * p + 1]);
        sbase = ex + ((b & 1) ? c[b & ~1] : 0);
        stot = s2[255];
    }
    __syncthreads();
    int d0 = b << 8;
    int nb = min(NPB, n - d0);
    int cnt_b = c[b];
    int csr0 = sbase + d0;   // pairs before + one self-loop per node before
    const unsigned int* pb = pairs + (size_t)b * PSTRIDE;

    __shared__ int deg[NPB];
    __shared__ int cur[NPB];
    __shared__ int tmp[NPB];
    deg[t] = (t < nb) ? 1 : 0;   // self-loop
    __syncthreads();
    for (int j = t; j < cnt_b; j += 256)
        atomicAdd(&deg[pb[j] >> 24], 1);
    __syncthreads();
    int v = deg[t];
    tmp[t] = v;
    __syncthreads();
    for (int o = 1; o < NPB; o <<= 1) {
        int u = (t >= o) ? tmp[t - o] : 0;
        __syncthreads();
        tmp[t] += u;
        __syncthreads();
    }
    int excl = tmp[t] - v;
    if (t < nb) {
        rowptr[d0 + t] = csr0 + excl;
        srcs[csr0 + excl] = d0 + t;   // self-loop at slot 0
        cur[t] = excl + 1;
    }
    __syncthreads();
    for (int j = t; j < cnt_b; j += 256) {
        unsigned int p = pb[j];
        int off = atomicAdd(&cur[p >> 24], 1);
        srcs[csr0 + off] = (int)(p & 0x00FFFFFFu);
    }
    if (b == 0 && t == 0) rowptr[n] = n + stot;
}

// --- tiled node GEMM: 64 nodes x 64 cols per block, 4x4 per thread ----------
// x-staging: linear coalesced global copy, scattered into padded xs[k][node]
// (stride 68 floats -> 8-way LDS banks instead of 64-way at stride 64).
template <int IN_DIM>
__global__ __launch_bounds__(256) void node_gemm(const float* __restrict__ x,
                                                 const float* __restrict__ W,
                                                 const float* __restrict__ a_src,
                                                 const float* __restrict__ a_dst,
                                                 const float* __restrict__ bias_in,
                                                 float slope_in,
                                                 unsigned short* __restrict__ h16,
                                                 float* __restrict__ al_s,
                                                 float* __restrict__ al_d,
                                                 int n) {
    __shared__ float Ws[IN_DIM * 64];
    __shared__ float xs[IN_DIM][XPAD];
    int t = threadIdx.x;
    int nbase = blockIdx.x * 64;

    for (int idx = t; idx < IN_DIM * 16; idx += 256)
        ((float4*)Ws)[idx] = ((const float4*)W)[idx];
    const float* xb = x + (size_t)nbase * IN_DIM;
    int lim = min(64, n - nbase) * IN_DIM;
    for (int idx = t; idx < 64 * IN_DIM; idx += 256) {
        int node = idx / IN_DIM;
        int k = idx - node * IN_DIM;
        float v = 0.0f;
        if (idx < lim) {
            v = xb[idx];                       // contiguous, fully coalesced
            if (bias_in) {
                v += bias_in[k];
                v = (v >= 0.0f) ? v : slope_in * v;
            }
        }
        xs[k][node] = v;
    }
    __syncthreads();

    int cg = t & 15;    // col group: cols 4cg..4cg+3
    int ng = t >> 4;    // node group: nodes 4ng..4ng+3
    float acc[4][4] = {};
#pragma unroll 8
    for (int k = 0; k < IN_DIM; k++) {
        float4 xv = *(const float4*)&xs[k][ng * 4];
        float4 wv = *(const float4*)&Ws[k * 64 + cg * 4];
        float xa[4] = {xv.x, xv.y, xv.z, xv.w};
        float wa[4] = {wv.x, wv.y, wv.z, wv.w};
#pragma unroll
        for (int i = 0; i < 4; i++)
#pragma unroll
            for (int j = 0; j < 4; j++)
                acc[i][j] += xa[i] * wa[j];
    }

    float4 as4 = *(const float4*)(a_src + cg * 4);
    float4 ad4 = *(const float4*)(a_dst + cg * 4);
#pragma unroll
    for (int i = 0; i < 4; i++) {
        int node = nbase + ng * 4 + i;
        if (node < n) {
            uint2 p;
            p.x = f2bf(acc[i][0]) | (f2bf(acc[i][1]) << 16);
            p.y = f2bf(acc[i][2]) | (f2bf(acc[i][3]) << 16);
            *(uint2*)(h16 + (size_t)node * 64 + cg * 4) = p;
        }
        float vs = acc[i][0] * as4.x + acc[i][1] * as4.y +
                   acc[i][2] * as4.z + acc[i][3] * as4.w;
        float vd = acc[i][0] * ad4.x + acc[i][1] * ad4.y +
                   acc[i][2] * ad4.z + acc[i][3] * ad4.w;
#pragma unroll
        for (int o = 8; o; o >>= 1) {
            vs += __shfl_xor(vs, o);
            vd += __shfl_xor(vd, o);
        }
        if (cg == 0 && node < n) { al_s[node] = vs; al_d[node] = vd; }
    }
}

// --- single-pass aggregate (R6 proven body): 8 lanes/node, unroll x4 --------
// out[node] = (sum_j exp(e_j)*h[src_j]) / (sum_j exp(e_j) + 1e-16)
__device__ __forceinline__ void bf8_fma(float* acc, uint4 q, float w) {
    acc[0] += w * __uint_as_float(q.x << 16);
    acc[1] += w * __uint_as_float(q.x & 0xFFFF0000u);
    acc[2] += w * __uint_as_float(q.y << 16);
    acc[3] += w * __uint_as_float(q.y & 0xFFFF0000u);
    acc[4] += w * __uint_as_float(q.z << 16);
    acc[5] += w * __uint_as_float(q.z & 0xFFFF0000u);
    acc[6] += w * __uint_as_float(q.w << 16);
    acc[7] += w * __uint_as_float(q.w & 0xFFFF0000u);
}

__global__ __launch_bounds__(256) void gat_aggregate(const int* __restrict__ rowptr,
                                                     const int* __restrict__ srcs,
                                                     const float* __restrict__ als,
                                                     const float* __restrict__ ald,
                                                     const unsigned short* __restrict__ h16,
                                                     float* __restrict__ hout,
                                                     int n) {
    int t = threadIdx.x;
    int sub = t >> 3, lane = t & 7;       // 32 nodes/block, 8 lanes/node
    int node = blockIdx.x * 32 + sub;
    if (node >= n) return;
    int beg = rowptr[node], end = rowptr[node + 1];
    float aldv = ald[node];
    const unsigned short* hb = h16 + lane * 8;

    float acc[8] = {};
    float sm = 0.0f;
    int j = beg;
    for (; j + 4 <= end; j += 4) {
        int s0 = srcs[j], s1 = srcs[j + 1], s2 = srcs[j + 2], s3 = srcs[j + 3];
        float e0 = als[s0] + aldv, e1 = als[s1] + aldv;
        float e2 = als[s2] + aldv, e3 = als[s3] + aldv;
        uint4 q0 = *(const uint4*)(hb + (size_t)s0 * 64);
        uint4 q1 = *(const uint4*)(hb + (size_t)s1 * 64);
        uint4 q2 = *(const uint4*)(hb + (size_t)s2 * 64);
        uint4 q3 = *(const uint4*)(hb + (size_t)s3 * 64);
        e0 = (e0 >= 0.0f) ? e0 : 0.2f * e0;
        e1 = (e1 >= 0.0f) ? e1 : 0.2f * e1;
        e2 = (e2 >= 0.0f) ? e2 : 0.2f * e2;
        e3 = (e3 >= 0.0f) ? e3 : 0.2f * e3;
        float w0 = __expf(e0), w1 = __expf(e1);
        float w2 = __expf(e2), w3 = __expf(e3);
        sm += (w0 + w1) + (w2 + w3);
        bf8_fma(acc, q0, w0);
        bf8_fma(acc, q1, w1);
        bf8_fma(acc, q2, w2);
        bf8_fma(acc, q3, w3);
    }
    for (; j < end; j++) {
        int s = srcs[j];
        float e = als[s] + aldv;
        e = (e >= 0.0f) ? e : 0.2f * e;
        float w = __expf(e);
        uint4 q = *(const uint4*)(hb + (size_t)s * 64);
        sm += w;
        bf8_fma(acc, q, w);
    }

    float inv = 1.0f / (sm + 1e-16f);
    float4 o0 = make_float4(acc[0] * inv, acc[1] * inv, acc[2] * inv, acc[3] * inv);
    float4 o1 = make_float4(acc[4] * inv, acc[5] * inv, acc[6] * inv, acc[7] * inv);
    float* op = hout + (size_t)node * 64 + lane * 8;
    *(float4*)op = o0;
    *(float4*)(op + 4) = o1;
}

// --- fused pool + FC: one block per graph, binary-search batch bounds -------
__global__ __launch_bounds__(256) void pool_fc(const float* __restrict__ hout,
                                               const float* __restrict__ b2,
                                               const int* __restrict__ batch,
                                               const float* __restrict__ fcW,
                                               const float* __restrict__ fcb,
                                               float* __restrict__ out, int n) {
    int g = blockIdx.x;
    int t = threadIdx.x;
    __shared__ int sLo, sHi;
    __shared__ float red[4][64];
    if (t == 0) {
        int lo = 0, hi = n;
        while (lo < hi) { int m = (lo + hi) >> 1; if (batch[m] < g) lo = m + 1; else hi = m; }
        sLo = lo;
    } else if (t == 64) {
        int lo = 0, hi = n;
        while (lo < hi) { int m = (lo + hi) >> 1; if (batch[m] < g + 1) lo = m + 1; else hi = m; }
        sHi = lo;
    }
    __syncthreads();
    int lo = sLo, hi = sHi;
    int wv = t >> 6, lane = t & 63;
    float acc = 0.0f;
    for (int node = lo + wv; node < hi; node += 4)
        acc += hout[(size_t)node * 64 + lane];
    red[wv][lane] = acc;
    __syncthreads();
    if (wv == 0) {
        float c = (float)(hi - lo);
        float s = red[0][lane] + red[1][lane] + red[2][lane] + red[3][lane];
        s += c * b2[lane];
        float cd = (c > 1.0f) ? c : 1.0f;
        float p = s / cd;
        float s0 = p * fcW[lane * 2 + 0];
        float s1 = p * fcW[lane * 2 + 1];
#pragma unroll
        for (int o = 32; o; o >>= 1) {
            s0 += __shfl_xor(s0, o);
            s1 += __shfl_xor(s1, o);
        }
        if (lane == 0) {
            out[g * 2 + 0] = s0 + fcb[0];
            out[g * 2 + 1] = s1 + fcb[1];
        }
    }
}

extern "C" void kernel_launch(void* const* d_in, const int* in_sizes, int n_in,
                              void* d_out, int out_size, void* d_ws, size_t ws_size,
                              hipStream_t stream) {
    const float* x    = (const float*)d_in[0];
    const int*   ei   = (const int*)d_in[1];
    const int*   batch= (const int*)d_in[2];
    const float* W1   = (const float*)d_in[3];
    const float* as1  = (const float*)d_in[4];
    const float* ad1  = (const float*)d_in[5];
    const float* b1   = (const float*)d_in[6];
    const float* W2   = (const float*)d_in[7];
    const float* as2  = (const float*)d_in[8];
    const float* ad2  = (const float*)d_in[9];
    const float* b2   = (const float*)d_in[10];
    const float* fcW  = (const float*)d_in[11];
    const float* fcb  = (const float*)d_in[12];
    float* out = (float*)d_out;

    const int N = in_sizes[2];       // 100000
    const int E = in_sizes[1] / 2;   // 1600000
    const int G = out_size / 2;      // 256
    const int tot = E + N;
    const int NB = (N + NPB - 1) / NPB;   // 391 buckets

    // ws layout (~54 MiB): pairs is packed uint32, stride-padded
    float* ws     = (float*)d_ws;
    float* bufO   = ws;                           // N*64 fp32        25.6 MB
    unsigned int* pairs = (unsigned int*)(bufO + (size_t)N * 64); // 7.2 MB
    float* als    = (float*)(pairs + (size_t)NB * PSTRIDE);  // N      0.4 MB
    float* ald    = als + N;                      // N                 0.4 MB
    int*   rowptr = (int*)(ald + N);              // N+1               0.4 MB
    int*   srcs   = rowptr + N + 1;               // tot               6.8 MB
    int*   bcur   = srcs + tot;                   // NB
    unsigned short* bufH16 = (unsigned short*)(bcur + NB);  // N*64   12.8 MB

    dim3 b256(256);
    int gInit = (NB + 255) / 256;
    int gPart = (E + EPB - 1) / EPB;
    int gGemm = (N + 63) / 64;
    int gAgg  = (N + 31) / 32;

    // ---- CSR build: single-pass fixed-stride partition + fill (edges only) --
    init_all<<<gInit, b256, 0, stream>>>(bcur, NB);
    partition<<<gPart, b256, 0, stream>>>(ei, E, NB, bcur, pairs);
    build_csr<<<NB, b256, 0, stream>>>(pairs, bcur, N, NB, rowptr, srcs);

    // ---- layer 1 ----
    node_gemm<72><<<gGemm, b256, 0, stream>>>(x, W1, as1, ad1, nullptr, 0.0f,
                                              bufH16, als, ald, N);
    gat_aggregate<<<gAgg, b256, 0, stream>>>(rowptr, srcs, als, ald, bufH16, bufO, N);

    // ---- layer 2 (input = leaky(bufO + b1, 0.01)) ----
    node_gemm<64><<<gGemm, b256, 0, stream>>>(bufO, W2, as2, ad2, b1, 0.01f,
                                              bufH16, als, ald, N);
    gat_aggregate<<<gAgg, b256, 0, stream>>>(rowptr, srcs, als, ald, bufH16, bufO, N);

    // ---- fused pool + fc ----
    pool_fc<<<G, b256, 0, stream>>>(bufO, b2, batch, fcW, fcb, out, N);
}